// Round 4
// baseline (298.230 us; speedup 1.0000x reference)
//
#include <hip/hip_runtime.h>
#include <hip/hip_bf16.h>
#include <math.h>

// B=2, C=128, T=5 (Tc=4 ctx), H=W=48, heads=64, PATCH=7 (pad 3), K=196.
#define BATCH 2
#define CCH 128
#define TT 5
#define TC 4
#define HH 48
#define WW 48
#define HWPIX 2304
#define NHEAD 64
#define PAD 3
#define XSTRIDE (TT*HWPIX)     // per-channel stride in x
#define ROWP 54                // 48 + 2*3 padded rows
#define COLP 56                // 48 + 2*3 padded cols, +2 slack for 16B align
#define PLANE (ROWP*COLP*NHEAD) // 193536 floats per (b,t) plane

// ---------------------------------------------------------------------------
// K1: projections -> PIXEL-MAJOR PADDED layouts (replicate borders written):
//   q_p  [b][2304][64]
//   phi_p/g_p[b][t][54][56][64]   (pad=3 materialized; cols 54,55 unused)
// Block = 4 hg-waves x 64 px. Weights wave-uniform -> s_load; x loads
// pixel-coalesced; stores h-contiguous float4.
// ---------------------------------------------------------------------------
__global__ __launch_bounds__(256) void proj_kernel(
    const float* __restrict__ x,
    const float* __restrict__ w_theta,
    const float* __restrict__ w_phi,
    const float* __restrict__ w_g,
    float* __restrict__ q_p,
    float* __restrict__ phi_p,
    float* __restrict__ g_p)
{
    const int bt  = blockIdx.y;          // 0..9
    const int b   = bt / TT;
    const int t   = bt % TT;
    const int pxl = threadIdx.x & 63;
    const int hg  = threadIdx.x >> 6;    // wave = head group
    const int h0  = hg * 16;
    const int pix = blockIdx.x * 64 + pxl;
    const int X   = pix / WW;
    const int Y   = pix % WW;
    const float* xp = x + ((size_t)(b * CCH) * TT + t) * HWPIX + pix;

    if (t == 0) {
        const float* wp = w_theta + (size_t)h0 * CCH;
        float acc[16];
#pragma unroll
        for (int j = 0; j < 16; ++j) acc[j] = 0.f;
        for (int c = 0; c < CCH; c += 2) {
            const float xv0 = xp[(size_t)(c + 0) * XSTRIDE];
            const float xv1 = xp[(size_t)(c + 1) * XSTRIDE];
#pragma unroll
            for (int j = 0; j < 16; ++j) {
                acc[j] = fmaf(wp[j * CCH + c + 0], xv0, acc[j]);
                acc[j] = fmaf(wp[j * CCH + c + 1], xv1, acc[j]);
            }
        }
        float4* d4 = (float4*)(q_p + ((size_t)b * HWPIX + pix) * NHEAD + h0);
#pragma unroll
        for (int j = 0; j < 4; ++j)
            d4[j] = make_float4(acc[4*j], acc[4*j+1], acc[4*j+2], acc[4*j+3]);
    } else {
        const float* wpp = w_phi + (size_t)h0 * CCH;
        const float* wgp = w_g   + (size_t)h0 * CCH;
        float ap[16], ag[16];
#pragma unroll
        for (int j = 0; j < 16; ++j) { ap[j] = 0.f; ag[j] = 0.f; }
        for (int c = 0; c < CCH; c += 2) {
            const float xv0 = xp[(size_t)(c + 0) * XSTRIDE];
            const float xv1 = xp[(size_t)(c + 1) * XSTRIDE];
#pragma unroll
            for (int j = 0; j < 16; ++j) {
                ap[j] = fmaf(wpp[j * CCH + c + 0], xv0, ap[j]);
                ap[j] = fmaf(wpp[j * CCH + c + 1], xv1, ap[j]);
                ag[j] = fmaf(wgp[j * CCH + c + 0], xv0, ag[j]);
                ag[j] = fmaf(wgp[j * CCH + c + 1], xv1, ag[j]);
            }
        }
        // replicate-padding store: interior pixels 1 site; edges 4; corners 16
        const int rs = (X == 0) ? 0 : (X + PAD);
        const int rn = (X == 0 || X == HH - 1) ? (PAD + 1) : 1;
        const int cs = (Y == 0) ? 0 : (Y + PAD);
        const int cn = (Y == 0 || Y == WW - 1) ? (PAD + 1) : 1;
        const size_t base = (size_t)(b * TC + (t - 1)) * PLANE;
        for (int r = 0; r < rn; ++r) {
            for (int c = 0; c < cn; ++c) {
                const size_t pos = base + ((size_t)(rs + r) * COLP + (cs + c)) * NHEAD + h0;
                float4* dp = (float4*)(phi_p + pos);
                float4* dg = (float4*)(g_p + pos);
#pragma unroll
                for (int j = 0; j < 4; ++j) {
                    dp[j] = make_float4(ap[4*j], ap[4*j+1], ap[4*j+2], ap[4*j+3]);
                    dg[j] = make_float4(ag[4*j], ag[4*j+1], ag[4*j+2], ag[4*j+3]);
                }
            }
        }
    }
}

// ---------------------------------------------------------------------------
// K2: fused attention + out-projection + residual.
// Block = (b, X, Y0) covering 16 pixels of one row. tid = px(4b)|sub(4b).
// Per t: stage 7x22x64 window (39.4KB, contiguous f4 copy) -> logits
// (ds_read_b128 over h, q in 64 VGPRs). Wave-local softmax over 196.
// Per t: stage g window -> y accumulation (thread owns (px, 4h)).
// Then 64->128 projection + residual, all stores coalesced.
// ---------------------------------------------------------------------------
__global__ __launch_bounds__(256) void attn_kernel(
    const float* __restrict__ q_p,
    const float* __restrict__ phi_p,
    const float* __restrict__ g_p,
    const float* __restrict__ x,
    const float* __restrict__ w_out,
    float* __restrict__ out)
{
    __shared__ float win[7 * 22 * NHEAD];   // 9856 floats = 38.5 KB
    __shared__ float ls[16][204];           // 196 logits/att per px (pad 204)
    __shared__ float y_lds[16][68];         // y[px][h] (pad 68)

    const int tid = threadIdx.x;
    const int px  = tid >> 4;               // 0..15
    const int sub = tid & 15;               // key-slot / h-chunk / c-chunk
    const int Y0  = blockIdx.x * 16;
    const int X   = blockIdx.y;
    const int b   = blockIdx.z;
    const int gpix = X * WW + Y0 + px;

    // q: 64 floats in regs (duplicated across sub — L1-served)
    float4 qr[16];
    {
        const float4* qs = (const float4*)(q_p + ((size_t)b * HWPIX + gpix) * NHEAD);
#pragma unroll
        for (int m = 0; m < 16; ++m) qr[m] = qs[m];
    }

    // ---- logits over all t ----
    for (int t = 0; t < TC; ++t) {
        __syncthreads();   // protect win from previous iteration's readers
        const float* src = phi_p + (size_t)(b * TC + t) * PLANE;
        for (int idx = tid; idx < 2464; idx += 256) {       // 7 rows x 352 f4
            const int i   = idx / 352;
            const int rem = idx - i * 352;
            const float4 v = *(const float4*)(src + ((size_t)(X + i) * COLP + Y0) * NHEAD + rem * 4);
            *(float4*)&win[idx * 4] = v;
        }
        __syncthreads();
#pragma unroll
        for (int r = 0; r < 4; ++r) {
            const int k = sub + 16 * r;
            if (k < 49) {
                const int i = k / 7;
                const int j = k - i * 7;
                const float4* wv = (const float4*)&win[(i * 22 + j + px) * NHEAD];
                float s = 0.f;
#pragma unroll
                for (int m = 0; m < 16; ++m) {
                    const float4 a = wv[m];
                    const float4 q = qr[m];
                    s += a.x*q.x + a.y*q.y + a.z*q.z + a.w*q.w;
                }
                ls[px][t * 49 + k] = s * 8.0f;   // * sqrt(64)
            }
        }
    }
    __syncthreads();

    // ---- softmax over 196 = 49 float4 chunks (thread handles 3-4 chunks) ----
    {
        float4 v0 = *(const float4*)&ls[px][(sub     ) * 4];
        float4 v1 = *(const float4*)&ls[px][(sub + 16) * 4];
        float4 v2 = *(const float4*)&ls[px][(sub + 32) * 4];
        const bool ex = (sub == 0);
        float4 v3 = ex ? *(const float4*)&ls[px][48 * 4]
                       : make_float4(-INFINITY, -INFINITY, -INFINITY, -INFINITY);
        float m = fmaxf(fmaxf(fmaxf(v0.x, v0.y), fmaxf(v0.z, v0.w)),
                        fmaxf(fmaxf(v1.x, v1.y), fmaxf(v1.z, v1.w)));
        m = fmaxf(m, fmaxf(fmaxf(v2.x, v2.y), fmaxf(v2.z, v2.w)));
        m = fmaxf(m, fmaxf(fmaxf(v3.x, v3.y), fmaxf(v3.z, v3.w)));
#pragma unroll
        for (int d = 1; d < 16; d <<= 1) m = fmaxf(m, __shfl_xor(m, d));
        v0.x = __expf(v0.x - m); v0.y = __expf(v0.y - m); v0.z = __expf(v0.z - m); v0.w = __expf(v0.w - m);
        v1.x = __expf(v1.x - m); v1.y = __expf(v1.y - m); v1.z = __expf(v1.z - m); v1.w = __expf(v1.w - m);
        v2.x = __expf(v2.x - m); v2.y = __expf(v2.y - m); v2.z = __expf(v2.z - m); v2.w = __expf(v2.w - m);
        float s3 = 0.f;
        if (ex) {
            v3.x = __expf(v3.x - m); v3.y = __expf(v3.y - m);
            v3.z = __expf(v3.z - m); v3.w = __expf(v3.w - m);
            s3 = v3.x + v3.y + v3.z + v3.w;
        }
        float sum = v0.x+v0.y+v0.z+v0.w + v1.x+v1.y+v1.z+v1.w
                  + v2.x+v2.y+v2.z+v2.w + s3;
#pragma unroll
        for (int d = 1; d < 16; d <<= 1) sum += __shfl_xor(sum, d);
        const float inv = 1.0f / sum;
        v0.x *= inv; v0.y *= inv; v0.z *= inv; v0.w *= inv;
        v1.x *= inv; v1.y *= inv; v1.z *= inv; v1.w *= inv;
        v2.x *= inv; v2.y *= inv; v2.z *= inv; v2.w *= inv;
        *(float4*)&ls[px][(sub     ) * 4] = v0;
        *(float4*)&ls[px][(sub + 16) * 4] = v1;
        *(float4*)&ls[px][(sub + 32) * 4] = v2;
        if (ex) {
            v3.x *= inv; v3.y *= inv; v3.z *= inv; v3.w *= inv;
            *(float4*)&ls[px][48 * 4] = v3;
        }
    }

    // ---- y accumulation: thread owns (px, h-chunk sub) ----
    float4 acc = make_float4(0.f, 0.f, 0.f, 0.f);
    for (int t = 0; t < TC; ++t) {
        __syncthreads();   // previous win readers done (incl. softmax's ls-only phase)
        const float* src = g_p + (size_t)(b * TC + t) * PLANE;
        for (int idx = tid; idx < 2464; idx += 256) {
            const int i   = idx / 352;
            const int rem = idx - i * 352;
            const float4 v = *(const float4*)(src + ((size_t)(X + i) * COLP + Y0) * NHEAD + rem * 4);
            *(float4*)&win[idx * 4] = v;
        }
        __syncthreads();
        const float* lsr = &ls[px][t * 49];
#pragma unroll
        for (int i = 0; i < 7; ++i) {
#pragma unroll
            for (int j = 0; j < 7; ++j) {
                const float a = lsr[i * 7 + j];
                const float4 gv = *(const float4*)&win[(i * 22 + j + px) * NHEAD + sub * 4];
                acc.x = fmaf(a, gv.x, acc.x);
                acc.y = fmaf(a, gv.y, acc.y);
                acc.z = fmaf(a, gv.z, acc.z);
                acc.w = fmaf(a, gv.w, acc.w);
            }
        }
    }
    *(float4*)&y_lds[px][sub * 4] = acc;
    __syncthreads();

    // ---- out projection + residual: thread owns (px, 8 channels) ----
    {
        const int c0 = sub * 8;
        float o[8];
#pragma unroll
        for (int jj = 0; jj < 8; ++jj) o[jj] = 0.f;
        for (int h = 0; h < NHEAD; h += 2) {
            const float yv0 = y_lds[px][h];
            const float yv1 = y_lds[px][h + 1];
#pragma unroll
            for (int jj = 0; jj < 8; ++jj) {
                o[jj] = fmaf(w_out[(size_t)(c0 + jj) * NHEAD + h    ], yv0, o[jj]);
                o[jj] = fmaf(w_out[(size_t)(c0 + jj) * NHEAD + h + 1], yv1, o[jj]);
            }
        }
#pragma unroll
        for (int jj = 0; jj < 8; ++jj) {
            const int c = c0 + jj;
            const float xi = x[((size_t)(b * CCH + c) * TT) * HWPIX + gpix];
            out[(size_t)(b * CCH + c) * HWPIX + gpix] = xi + o[jj];
        }
    }
}

// ---------------------------------------------------------------------------
extern "C" void kernel_launch(void* const* d_in, const int* in_sizes, int n_in,
                              void* d_out, int out_size, void* d_ws, size_t ws_size,
                              hipStream_t stream)
{
    const float* x       = (const float*)d_in[0];
    const float* w_theta = (const float*)d_in[1];
    const float* w_phi   = (const float*)d_in[2];
    const float* w_g     = (const float*)d_in[3];
    const float* w_out   = (const float*)d_in[4];
    float* out = (float*)d_out;

    float* ws    = (float*)d_ws;
    float* q_p   = ws;                                    // 2*2304*64      = 294912
    float* phi_p = q_p + (size_t)BATCH * HWPIX * NHEAD;   // 2*4*193536     = 1548288
    float* g_p   = phi_p + (size_t)BATCH * TC * PLANE;    // 2*4*193536     = 1548288
                                                          // total ~13.6 MB

    dim3 g1(HWPIX / 64, BATCH * TT);            // (36, 10)
    proj_kernel<<<g1, 256, 0, stream>>>(x, w_theta, w_phi, w_g, q_p, phi_p, g_p);

    dim3 g2(WW / 16, HH, BATCH);                // (3, 48, 2) = 288 blocks
    attn_kernel<<<g2, 256, 0, stream>>>(q_p, phi_p, g_p, x, w_out, out);
}

// Round 5
// 191.911 us; speedup vs baseline: 1.5540x; 1.5540x over previous
//
#include <hip/hip_runtime.h>
#include <hip/hip_bf16.h>
#include <math.h>

// B=2, C=128, T=5 (Tc=4 ctx), H=W=48, heads=64, PATCH=7 (pad 3), K=196.
#define BATCH 2
#define CCH 128
#define TT 5
#define TC 4
#define HH 48
#define WW 48
#define HWPIX 2304
#define NHEAD 64
#define PAD 3
#define XSTRIDE (TT*HWPIX)     // per-channel stride in x
#define ROWP 54                // 48 + 2*3 padded rows
#define COLP 56                // 48 + 2*3 padded cols (+2 align slack)
#define PLANE (ROWP*COLP*NHEAD) // 193536 floats per (b,t) plane

// ---------------------------------------------------------------------------
// K0: transpose weights [64h][128c] -> [32cq][64h] float4 (4 consecutive c
// per lane). One block; loads coalesced over cq.
// ---------------------------------------------------------------------------
__global__ __launch_bounds__(256) void wtrans_kernel(
    const float* __restrict__ w_theta,
    const float* __restrict__ w_phi,
    const float* __restrict__ w_g,
    float4* __restrict__ wq4,
    float4* __restrict__ wp4,
    float4* __restrict__ wg4)
{
    const int tid = threadIdx.x;
    const float* srcs[3] = {w_theta, w_phi, w_g};
    float4*      dsts[3] = {wq4, wp4, wg4};
#pragma unroll
    for (int a = 0; a < 3; ++a) {
        const float* s = srcs[a];
        float4*      d = dsts[a];
#pragma unroll
        for (int r = 0; r < 8; ++r) {
            const int idx = r * 256 + tid;   // 0..2047
            const int h   = idx >> 5;        // 0..63
            const int cq  = idx & 31;        // 0..31
            const float4 v = *(const float4*)(s + h * CCH + cq * 4);
            d[cq * 64 + h] = v;
        }
    }
}

// ---------------------------------------------------------------------------
// K1: projections, lane = head. Block = 4 waves x 8 pixels (32 px/block).
// Per 4-c chunk: 2 coalesced float4 weight loads (lane-indexed) + 8 wave-
// uniform x loads (scalar pipe) + 64 FMAs. Outputs:
//   q_p[b][2304][64];  phi_p/g_p[b][t][54][56][64] with replicate borders.
// ---------------------------------------------------------------------------
__global__ __launch_bounds__(256) void proj_kernel(
    const float* __restrict__ x,
    const float4* __restrict__ wq4,
    const float4* __restrict__ wp4,
    const float4* __restrict__ wg4,
    float* __restrict__ q_p,
    float* __restrict__ phi_p,
    float* __restrict__ g_p)
{
    const int bt   = blockIdx.y;        // 0..9
    const int b    = bt / TT;
    const int t    = bt % TT;
    const int lane = threadIdx.x & 63;
    const int wv   = __builtin_amdgcn_readfirstlane(threadIdx.x >> 6);
    const int p0   = blockIdx.x * 32 + wv * 8;
    const float* xw = x + ((size_t)(b * CCH) * TT + t) * HWPIX + p0;

    if (t == 0) {
        float acc[8];
#pragma unroll
        for (int p = 0; p < 8; ++p) acc[p] = 0.f;
        for (int cq = 0; cq < 32; ++cq) {
            const float4 wq = wq4[(cq << 6) | lane];
            const float wqa[4] = {wq.x, wq.y, wq.z, wq.w};
            const float* xc = xw + (size_t)(cq * 4) * XSTRIDE;
            float xs[4][8];
#pragma unroll
            for (int i = 0; i < 4; ++i) {
                const float4 a  = *(const float4*)(xc + (size_t)i * XSTRIDE);
                const float4 bb = *(const float4*)(xc + (size_t)i * XSTRIDE + 4);
                xs[i][0]=a.x; xs[i][1]=a.y; xs[i][2]=a.z; xs[i][3]=a.w;
                xs[i][4]=bb.x; xs[i][5]=bb.y; xs[i][6]=bb.z; xs[i][7]=bb.w;
            }
#pragma unroll
            for (int i = 0; i < 4; ++i)
#pragma unroll
                for (int p = 0; p < 8; ++p)
                    acc[p] = fmaf(wqa[i], xs[i][p], acc[p]);
        }
#pragma unroll
        for (int p = 0; p < 8; ++p)
            q_p[((size_t)b * HWPIX + p0 + p) * NHEAD + lane] = acc[p];
    } else {
        float accp[8], accg[8];
#pragma unroll
        for (int p = 0; p < 8; ++p) { accp[p] = 0.f; accg[p] = 0.f; }
        for (int cq = 0; cq < 32; ++cq) {
            const float4 wp = wp4[(cq << 6) | lane];
            const float4 wg = wg4[(cq << 6) | lane];
            const float wpa[4] = {wp.x, wp.y, wp.z, wp.w};
            const float wga[4] = {wg.x, wg.y, wg.z, wg.w};
            const float* xc = xw + (size_t)(cq * 4) * XSTRIDE;
            float xs[4][8];
#pragma unroll
            for (int i = 0; i < 4; ++i) {
                const float4 a  = *(const float4*)(xc + (size_t)i * XSTRIDE);
                const float4 bb = *(const float4*)(xc + (size_t)i * XSTRIDE + 4);
                xs[i][0]=a.x; xs[i][1]=a.y; xs[i][2]=a.z; xs[i][3]=a.w;
                xs[i][4]=bb.x; xs[i][5]=bb.y; xs[i][6]=bb.z; xs[i][7]=bb.w;
            }
#pragma unroll
            for (int i = 0; i < 4; ++i)
#pragma unroll
                for (int p = 0; p < 8; ++p) {
                    accp[p] = fmaf(wpa[i], xs[i][p], accp[p]);
                    accg[p] = fmaf(wga[i], xs[i][p], accg[p]);
                }
        }
        const size_t base = (size_t)(b * TC + (t - 1)) * PLANE;
#pragma unroll
        for (int p = 0; p < 8; ++p) {
            const int pix = p0 + p;
            const int X = pix / WW;
            const int Y = pix % WW;
            const int rs = (X == 0) ? 0 : (X + PAD);
            const int rn = (X == 0 || X == HH - 1) ? (PAD + 1) : 1;
            const int cs = (Y == 0) ? 0 : (Y + PAD);
            const int cn = (Y == 0 || Y == WW - 1) ? (PAD + 1) : 1;
            for (int r = 0; r < rn; ++r)
                for (int c = 0; c < cn; ++c) {
                    const size_t pos = base + ((size_t)(rs + r) * COLP + (cs + c)) * NHEAD + lane;
                    phi_p[pos] = accp[p];
                    g_p[pos]   = accg[p];
                }
        }
    }
}

// ---------------------------------------------------------------------------
// K2: fused attention + out-projection + residual (unchanged from R4).
// Block = (b, X, Y0) covering 16 pixels of one row. tid = px(4b)|sub(4b).
// ---------------------------------------------------------------------------
__global__ __launch_bounds__(256) void attn_kernel(
    const float* __restrict__ q_p,
    const float* __restrict__ phi_p,
    const float* __restrict__ g_p,
    const float* __restrict__ x,
    const float* __restrict__ w_out,
    float* __restrict__ out)
{
    __shared__ float win[7 * 22 * NHEAD];   // 9856 floats = 38.5 KB
    __shared__ float ls[16][204];           // 196 logits/att per px
    __shared__ float y_lds[16][68];         // y[px][h]

    const int tid = threadIdx.x;
    const int px  = tid >> 4;
    const int sub = tid & 15;
    const int Y0  = blockIdx.x * 16;
    const int X   = blockIdx.y;
    const int b   = blockIdx.z;
    const int gpix = X * WW + Y0 + px;

    float4 qr[16];
    {
        const float4* qs = (const float4*)(q_p + ((size_t)b * HWPIX + gpix) * NHEAD);
#pragma unroll
        for (int m = 0; m < 16; ++m) qr[m] = qs[m];
    }

    // ---- logits over all t ----
    for (int t = 0; t < TC; ++t) {
        __syncthreads();
        const float* src = phi_p + (size_t)(b * TC + t) * PLANE;
        for (int idx = tid; idx < 2464; idx += 256) {       // 7 rows x 352 f4
            const int i   = idx / 352;
            const int rem = idx - i * 352;
            const float4 v = *(const float4*)(src + ((size_t)(X + i) * COLP + Y0) * NHEAD + rem * 4);
            *(float4*)&win[idx * 4] = v;
        }
        __syncthreads();
#pragma unroll
        for (int r = 0; r < 4; ++r) {
            const int k = sub + 16 * r;
            if (k < 49) {
                const int i = k / 7;
                const int j = k - i * 7;
                const float4* wvp = (const float4*)&win[(i * 22 + j + px) * NHEAD];
                float s = 0.f;
#pragma unroll
                for (int m = 0; m < 16; ++m) {
                    const float4 a = wvp[m];
                    const float4 q = qr[m];
                    s += a.x*q.x + a.y*q.y + a.z*q.z + a.w*q.w;
                }
                ls[px][t * 49 + k] = s * 8.0f;   // * sqrt(64)
            }
        }
    }
    __syncthreads();

    // ---- softmax over 196 ----
    {
        float4 v0 = *(const float4*)&ls[px][(sub     ) * 4];
        float4 v1 = *(const float4*)&ls[px][(sub + 16) * 4];
        float4 v2 = *(const float4*)&ls[px][(sub + 32) * 4];
        const bool ex = (sub == 0);
        float4 v3 = ex ? *(const float4*)&ls[px][48 * 4]
                       : make_float4(-INFINITY, -INFINITY, -INFINITY, -INFINITY);
        float m = fmaxf(fmaxf(fmaxf(v0.x, v0.y), fmaxf(v0.z, v0.w)),
                        fmaxf(fmaxf(v1.x, v1.y), fmaxf(v1.z, v1.w)));
        m = fmaxf(m, fmaxf(fmaxf(v2.x, v2.y), fmaxf(v2.z, v2.w)));
        m = fmaxf(m, fmaxf(fmaxf(v3.x, v3.y), fmaxf(v3.z, v3.w)));
#pragma unroll
        for (int d = 1; d < 16; d <<= 1) m = fmaxf(m, __shfl_xor(m, d));
        v0.x = __expf(v0.x - m); v0.y = __expf(v0.y - m); v0.z = __expf(v0.z - m); v0.w = __expf(v0.w - m);
        v1.x = __expf(v1.x - m); v1.y = __expf(v1.y - m); v1.z = __expf(v1.z - m); v1.w = __expf(v1.w - m);
        v2.x = __expf(v2.x - m); v2.y = __expf(v2.y - m); v2.z = __expf(v2.z - m); v2.w = __expf(v2.w - m);
        float s3 = 0.f;
        if (ex) {
            v3.x = __expf(v3.x - m); v3.y = __expf(v3.y - m);
            v3.z = __expf(v3.z - m); v3.w = __expf(v3.w - m);
            s3 = v3.x + v3.y + v3.z + v3.w;
        }
        float sum = v0.x+v0.y+v0.z+v0.w + v1.x+v1.y+v1.z+v1.w
                  + v2.x+v2.y+v2.z+v2.w + s3;
#pragma unroll
        for (int d = 1; d < 16; d <<= 1) sum += __shfl_xor(sum, d);
        const float inv = 1.0f / sum;
        v0.x *= inv; v0.y *= inv; v0.z *= inv; v0.w *= inv;
        v1.x *= inv; v1.y *= inv; v1.z *= inv; v1.w *= inv;
        v2.x *= inv; v2.y *= inv; v2.z *= inv; v2.w *= inv;
        *(float4*)&ls[px][(sub     ) * 4] = v0;
        *(float4*)&ls[px][(sub + 16) * 4] = v1;
        *(float4*)&ls[px][(sub + 32) * 4] = v2;
        if (ex) {
            v3.x *= inv; v3.y *= inv; v3.z *= inv; v3.w *= inv;
            *(float4*)&ls[px][48 * 4] = v3;
        }
    }

    // ---- y accumulation ----
    float4 acc = make_float4(0.f, 0.f, 0.f, 0.f);
    for (int t = 0; t < TC; ++t) {
        __syncthreads();
        const float* src = g_p + (size_t)(b * TC + t) * PLANE;
        for (int idx = tid; idx < 2464; idx += 256) {
            const int i   = idx / 352;
            const int rem = idx - i * 352;
            const float4 v = *(const float4*)(src + ((size_t)(X + i) * COLP + Y0) * NHEAD + rem * 4);
            *(float4*)&win[idx * 4] = v;
        }
        __syncthreads();
        const float* lsr = &ls[px][t * 49];
#pragma unroll
        for (int i = 0; i < 7; ++i) {
#pragma unroll
            for (int j = 0; j < 7; ++j) {
                const float a = lsr[i * 7 + j];
                const float4 gv = *(const float4*)&win[(i * 22 + j + px) * NHEAD + sub * 4];
                acc.x = fmaf(a, gv.x, acc.x);
                acc.y = fmaf(a, gv.y, acc.y);
                acc.z = fmaf(a, gv.z, acc.z);
                acc.w = fmaf(a, gv.w, acc.w);
            }
        }
    }
    *(float4*)&y_lds[px][sub * 4] = acc;
    __syncthreads();

    // ---- out projection + residual ----
    {
        const int c0 = sub * 8;
        float o[8];
#pragma unroll
        for (int jj = 0; jj < 8; ++jj) o[jj] = 0.f;
        for (int h = 0; h < NHEAD; h += 2) {
            const float yv0 = y_lds[px][h];
            const float yv1 = y_lds[px][h + 1];
#pragma unroll
            for (int jj = 0; jj < 8; ++jj) {
                o[jj] = fmaf(w_out[(size_t)(c0 + jj) * NHEAD + h    ], yv0, o[jj]);
                o[jj] = fmaf(w_out[(size_t)(c0 + jj) * NHEAD + h + 1], yv1, o[jj]);
            }
        }
#pragma unroll
        for (int jj = 0; jj < 8; ++jj) {
            const int c = c0 + jj;
            const float xi = x[((size_t)(b * CCH + c) * TT) * HWPIX + gpix];
            out[(size_t)(b * CCH + c) * HWPIX + gpix] = xi + o[jj];
        }
    }
}

// ---------------------------------------------------------------------------
extern "C" void kernel_launch(void* const* d_in, const int* in_sizes, int n_in,
                              void* d_out, int out_size, void* d_ws, size_t ws_size,
                              hipStream_t stream)
{
    const float* x       = (const float*)d_in[0];
    const float* w_theta = (const float*)d_in[1];
    const float* w_phi   = (const float*)d_in[2];
    const float* w_g     = (const float*)d_in[3];
    const float* w_out   = (const float*)d_in[4];
    float* out = (float*)d_out;

    float* ws    = (float*)d_ws;
    float* q_p   = ws;                                    // 2*2304*64
    float* phi_p = q_p + (size_t)BATCH * HWPIX * NHEAD;
    float* g_p   = phi_p + (size_t)BATCH * TC * PLANE;
    float4* wq4  = (float4*)(g_p + (size_t)BATCH * TC * PLANE);
    float4* wp4  = wq4 + 2048;
    float4* wg4  = wp4 + 2048;

    wtrans_kernel<<<1, 256, 0, stream>>>(w_theta, w_phi, w_g, wq4, wp4, wg4);

    dim3 g1(HWPIX / 32, BATCH * TT);            // (72, 10)
    proj_kernel<<<g1, 256, 0, stream>>>(x, wq4, wp4, wg4, q_p, phi_p, g_p);

    dim3 g2(WW / 16, HH, BATCH);                // (3, 48, 2) = 288 blocks
    attn_kernel<<<g2, 256, 0, stream>>>(q_p, phi_p, g_p, x, w_out, out);
}

// Round 6
// 146.509 us; speedup vs baseline: 2.0356x; 1.3099x over previous
//
#include <hip/hip_runtime.h>
#include <hip/hip_bf16.h>
#include <math.h>

// B=2, C=128, T=5 (Tc=4 ctx), H=W=48, heads=64, PATCH=7 (pad 3), K=196.
#define BATCH 2
#define CCH 128
#define TT 5
#define TC 4
#define HH 48
#define WW 48
#define HWPIX 2304
#define NHEAD 64
#define PAD 3
#define XSTRIDE (TT*HWPIX)      // per-channel stride in x
#define ROWP 54                 // 48 + 2*3 padded rows
#define COLP 56                 // 48 + 2*3 padded cols (+2 align slack)
#define PLANE (ROWP*COLP*NHEAD) // floats per (b,t) plane

// ---------------------------------------------------------------------------
// K0: weight reshapes. wq4/wp4/wg4: [32cq][64h] float4 (4 consecutive c per
// lane, lane=head). wo_t: [64h][128c] transpose of w_out for coalesced reads.
// ---------------------------------------------------------------------------
__global__ __launch_bounds__(256) void wtrans_kernel(
    const float* __restrict__ w_theta,
    const float* __restrict__ w_phi,
    const float* __restrict__ w_g,
    const float* __restrict__ w_out,
    float4* __restrict__ wq4,
    float4* __restrict__ wp4,
    float4* __restrict__ wg4,
    float* __restrict__ wo_t)
{
    const int tid = threadIdx.x;
    const float* srcs[3] = {w_theta, w_phi, w_g};
    float4*      dsts[3] = {wq4, wp4, wg4};
#pragma unroll
    for (int a = 0; a < 3; ++a) {
#pragma unroll
        for (int r = 0; r < 8; ++r) {
            const int idx = r * 256 + tid;   // 0..2047
            const int h   = idx >> 5;
            const int cq  = idx & 31;
            dsts[a][cq * 64 + h] = *(const float4*)(srcs[a] + h * CCH + cq * 4);
        }
    }
#pragma unroll
    for (int r = 0; r < 8; ++r) {
        const int idx = r * 256 + tid;       // 0..2047
        const int c   = idx >> 4;
        const int hq  = idx & 15;
        const float4 v = *(const float4*)(w_out + c * NHEAD + hq * 4);
        wo_t[(hq * 4 + 0) * CCH + c] = v.x;
        wo_t[(hq * 4 + 1) * CCH + c] = v.y;
        wo_t[(hq * 4 + 2) * CCH + c] = v.z;
        wo_t[(hq * 4 + 3) * CCH + c] = v.w;
    }
}

// ---------------------------------------------------------------------------
// K1: projections, lane = head, 4 px per wave (16 px/block, 1440 blocks ->
// ~5.6 waves/SIMD for latency hiding). Per 4-c chunk: 1-2 float4 weight
// vector loads + 4 wave-uniform x f4 scalar loads + 16/32 FMAs.
//   q_p[b][2304][64]; phi_p/g_p[b][t][54][56][64] replicate borders.
// ---------------------------------------------------------------------------
__global__ __launch_bounds__(256) void proj_kernel(
    const float* __restrict__ x,
    const float4* __restrict__ wq4,
    const float4* __restrict__ wp4,
    const float4* __restrict__ wg4,
    float* __restrict__ q_p,
    float* __restrict__ phi_p,
    float* __restrict__ g_p)
{
    const int bt   = blockIdx.y;        // 0..9
    const int b    = bt / TT;
    const int t    = bt % TT;
    const int lane = threadIdx.x & 63;
    const int wv   = __builtin_amdgcn_readfirstlane(threadIdx.x >> 6);
    const int p0   = blockIdx.x * 16 + wv * 4;
    const float* xw = x + ((size_t)(b * CCH) * TT + t) * HWPIX + p0;

    if (t == 0) {
        float acc[4] = {0.f, 0.f, 0.f, 0.f};
#pragma unroll 2
        for (int cq = 0; cq < 32; ++cq) {
            const float4 wq = wq4[(cq << 6) | lane];
            const float wqa[4] = {wq.x, wq.y, wq.z, wq.w};
            const float* xc = xw + (size_t)(cq * 4) * XSTRIDE;
#pragma unroll
            for (int i = 0; i < 4; ++i) {
                const float4 xv = *(const float4*)(xc + (size_t)i * XSTRIDE);
                acc[0] = fmaf(wqa[i], xv.x, acc[0]);
                acc[1] = fmaf(wqa[i], xv.y, acc[1]);
                acc[2] = fmaf(wqa[i], xv.z, acc[2]);
                acc[3] = fmaf(wqa[i], xv.w, acc[3]);
            }
        }
#pragma unroll
        for (int p = 0; p < 4; ++p)
            q_p[((size_t)b * HWPIX + p0 + p) * NHEAD + lane] = acc[p];
    } else {
        float accp[4] = {0.f, 0.f, 0.f, 0.f};
        float accg[4] = {0.f, 0.f, 0.f, 0.f};
#pragma unroll 2
        for (int cq = 0; cq < 32; ++cq) {
            const float4 wp = wp4[(cq << 6) | lane];
            const float4 wg = wg4[(cq << 6) | lane];
            const float wpa[4] = {wp.x, wp.y, wp.z, wp.w};
            const float wga[4] = {wg.x, wg.y, wg.z, wg.w};
            const float* xc = xw + (size_t)(cq * 4) * XSTRIDE;
#pragma unroll
            for (int i = 0; i < 4; ++i) {
                const float4 xv = *(const float4*)(xc + (size_t)i * XSTRIDE);
                accp[0] = fmaf(wpa[i], xv.x, accp[0]);
                accp[1] = fmaf(wpa[i], xv.y, accp[1]);
                accp[2] = fmaf(wpa[i], xv.z, accp[2]);
                accp[3] = fmaf(wpa[i], xv.w, accp[3]);
                accg[0] = fmaf(wga[i], xv.x, accg[0]);
                accg[1] = fmaf(wga[i], xv.y, accg[1]);
                accg[2] = fmaf(wga[i], xv.z, accg[2]);
                accg[3] = fmaf(wga[i], xv.w, accg[3]);
            }
        }
        const size_t base = (size_t)(b * TC + (t - 1)) * PLANE;
#pragma unroll
        for (int p = 0; p < 4; ++p) {
            const int pix = p0 + p;
            const int X = pix / WW;
            const int Y = pix % WW;
            const int rs = (X == 0) ? 0 : (X + PAD);
            const int rn = (X == 0 || X == HH - 1) ? (PAD + 1) : 1;
            const int cs = (Y == 0) ? 0 : (Y + PAD);
            const int cn = (Y == 0 || Y == WW - 1) ? (PAD + 1) : 1;
            for (int r = 0; r < rn; ++r)
                for (int c = 0; c < cn; ++c) {
                    const size_t pos = base + ((size_t)(rs + r) * COLP + (cs + c)) * NHEAD + lane;
                    phi_p[pos] = accp[p];
                    g_p[pos]   = accg[p];
                }
        }
    }
}

// ---------------------------------------------------------------------------
// K2: fused attention + out-projection + residual.
// Block = (b, X, Y0): 16 pixels of one row. tid = px(4b)|sub(4b).
// win holds one t's 7x22x64 window, SWIZZLED: h-chunk m of flat row r lives
// at 16B-slot (m+r)&15 -> rows rotate bank groups -> no LDS conflicts.
// y aliases win after the last g window is consumed.
// ---------------------------------------------------------------------------
__global__ __launch_bounds__(256) void attn_kernel(
    const float* __restrict__ q_p,
    const float* __restrict__ phi_p,
    const float* __restrict__ g_p,
    const float* __restrict__ x,
    const float* __restrict__ wo_t,
    float* __restrict__ out)
{
    __shared__ float win[154 * NHEAD];      // 38.5 KB, swizzled
    __shared__ float ls[16][200];           // 196 logits/att per px

    float* y_al = win;                      // [16][68] alias, used after t-loop

    const int tid = threadIdx.x;
    const int px  = tid >> 4;
    const int sub = tid & 15;
    const int Y0  = blockIdx.x * 16;
    const int X   = blockIdx.y;
    const int b   = blockIdx.z;
    const int gpix = X * WW + Y0 + px;

    float4 qr[16];
    {
        const float4* qs = (const float4*)(q_p + ((size_t)b * HWPIX + gpix) * NHEAD);
#pragma unroll
        for (int m = 0; m < 16; ++m) qr[m] = qs[m];
    }

    // ---- phase 1: logits over all t ----
    for (int t = 0; t < TC; ++t) {
        __syncthreads();
        const float* src = phi_p + (size_t)(b * TC + t) * PLANE;
        for (int idx = tid; idx < 2464; idx += 256) {     // 154 rows x 16 chunks
            const int i   = idx / 352;
            const int rem = idx - i * 352;
            const int c   = rem >> 4;
            const int m   = rem & 15;
            const int row = i * 22 + c;
            const float4 v = *(const float4*)(src + ((size_t)(X + i) * COLP + Y0 + c) * NHEAD + m * 4);
            *(float4*)&win[row * 64 + (((m + row) & 15) << 2)] = v;
        }
        __syncthreads();
#pragma unroll
        for (int r = 0; r < 4; ++r) {
            const int k = sub + 16 * r;
            if (k < 49) {
                const int i = k / 7;
                const int j = k - i * 7;
                const int row = i * 22 + j + px;
                const float* base = &win[row * 64];
                float s = 0.f;
#pragma unroll
                for (int m = 0; m < 16; ++m) {
                    const int sl = (m + row) & 15;
                    const float4 a = *(const float4*)&base[sl << 2];
                    const float4 q = qr[m];
                    s += a.x*q.x + a.y*q.y + a.z*q.z + a.w*q.w;
                }
                ls[px][t * 49 + k] = s * 8.0f;   // * sqrt(64)
            }
        }
    }
    __syncthreads();

    // ---- softmax over 196 = 49 float4 chunks ----
    {
        float4 v0 = *(const float4*)&ls[px][(sub     ) * 4];
        float4 v1 = *(const float4*)&ls[px][(sub + 16) * 4];
        float4 v2 = *(const float4*)&ls[px][(sub + 32) * 4];
        const bool ex = (sub == 0);
        float4 v3 = ex ? *(const float4*)&ls[px][48 * 4]
                       : make_float4(-INFINITY, -INFINITY, -INFINITY, -INFINITY);
        float m = fmaxf(fmaxf(fmaxf(v0.x, v0.y), fmaxf(v0.z, v0.w)),
                        fmaxf(fmaxf(v1.x, v1.y), fmaxf(v1.z, v1.w)));
        m = fmaxf(m, fmaxf(fmaxf(v2.x, v2.y), fmaxf(v2.z, v2.w)));
        m = fmaxf(m, fmaxf(fmaxf(v3.x, v3.y), fmaxf(v3.z, v3.w)));
#pragma unroll
        for (int d = 1; d < 16; d <<= 1) m = fmaxf(m, __shfl_xor(m, d));
        v0.x = __expf(v0.x - m); v0.y = __expf(v0.y - m); v0.z = __expf(v0.z - m); v0.w = __expf(v0.w - m);
        v1.x = __expf(v1.x - m); v1.y = __expf(v1.y - m); v1.z = __expf(v1.z - m); v1.w = __expf(v1.w - m);
        v2.x = __expf(v2.x - m); v2.y = __expf(v2.y - m); v2.z = __expf(v2.z - m); v2.w = __expf(v2.w - m);
        float s3 = 0.f;
        if (ex) {
            v3.x = __expf(v3.x - m); v3.y = __expf(v3.y - m);
            v3.z = __expf(v3.z - m); v3.w = __expf(v3.w - m);
            s3 = v3.x + v3.y + v3.z + v3.w;
        }
        float sum = v0.x+v0.y+v0.z+v0.w + v1.x+v1.y+v1.z+v1.w
                  + v2.x+v2.y+v2.z+v2.w + s3;
#pragma unroll
        for (int d = 1; d < 16; d <<= 1) sum += __shfl_xor(sum, d);
        const float inv = 1.0f / sum;
        v0.x *= inv; v0.y *= inv; v0.z *= inv; v0.w *= inv;
        v1.x *= inv; v1.y *= inv; v1.z *= inv; v1.w *= inv;
        v2.x *= inv; v2.y *= inv; v2.z *= inv; v2.w *= inv;
        *(float4*)&ls[px][(sub     ) * 4] = v0;
        *(float4*)&ls[px][(sub + 16) * 4] = v1;
        *(float4*)&ls[px][(sub + 32) * 4] = v2;
        if (ex) {
            v3.x *= inv; v3.y *= inv; v3.z *= inv; v3.w *= inv;
            *(float4*)&ls[px][48 * 4] = v3;
        }
    }

    // ---- phase 2: y accumulation (thread owns px, h-chunk sub) ----
    float4 acc = make_float4(0.f, 0.f, 0.f, 0.f);
    for (int t = 0; t < TC; ++t) {
        __syncthreads();
        const float* src = g_p + (size_t)(b * TC + t) * PLANE;
        for (int idx = tid; idx < 2464; idx += 256) {
            const int i   = idx / 352;
            const int rem = idx - i * 352;
            const int c   = rem >> 4;
            const int m   = rem & 15;
            const int row = i * 22 + c;
            const float4 v = *(const float4*)(src + ((size_t)(X + i) * COLP + Y0 + c) * NHEAD + m * 4);
            *(float4*)&win[row * 64 + (((m + row) & 15) << 2)] = v;
        }
        __syncthreads();
        const float* lsr = &ls[px][t * 49];
#pragma unroll
        for (int i = 0; i < 7; ++i) {
#pragma unroll
            for (int j = 0; j < 7; ++j) {
                const int row = i * 22 + j + px;
                const float a = lsr[i * 7 + j];
                const float4 gv = *(const float4*)&win[row * 64 + (((sub + row) & 15) << 2)];
                acc.x = fmaf(a, gv.x, acc.x);
                acc.y = fmaf(a, gv.y, acc.y);
                acc.z = fmaf(a, gv.z, acc.z);
                acc.w = fmaf(a, gv.w, acc.w);
            }
        }
    }
    __syncthreads();                       // all win reads done before y alias
    *(float4*)&y_al[px * 68 + sub * 4] = acc;
    __syncthreads();

    // ---- out projection + residual: wo_t[h][c] coalesced 512B runs ----
    {
        const int c0 = sub * 8;
        float o[8];
#pragma unroll
        for (int jj = 0; jj < 8; ++jj) o[jj] = 0.f;
        for (int h0 = 0; h0 < NHEAD; h0 += 4) {
            float yv[4];
            *(float4*)yv = *(const float4*)&y_al[px * 68 + h0];
#pragma unroll
            for (int e = 0; e < 4; ++e) {
                const float4 w0 = *(const float4*)(wo_t + (size_t)(h0 + e) * CCH + c0);
                const float4 w1 = *(const float4*)(wo_t + (size_t)(h0 + e) * CCH + c0 + 4);
                const float yy = yv[e];
                o[0] = fmaf(w0.x, yy, o[0]);
                o[1] = fmaf(w0.y, yy, o[1]);
                o[2] = fmaf(w0.z, yy, o[2]);
                o[3] = fmaf(w0.w, yy, o[3]);
                o[4] = fmaf(w1.x, yy, o[4]);
                o[5] = fmaf(w1.y, yy, o[5]);
                o[6] = fmaf(w1.z, yy, o[6]);
                o[7] = fmaf(w1.w, yy, o[7]);
            }
        }
#pragma unroll
        for (int jj = 0; jj < 8; ++jj) {
            const int c = c0 + jj;
            const float xi = x[((size_t)(b * CCH + c) * TT) * HWPIX + gpix];
            out[(size_t)(b * CCH + c) * HWPIX + gpix] = xi + o[jj];
        }
    }
}

// ---------------------------------------------------------------------------
extern "C" void kernel_launch(void* const* d_in, const int* in_sizes, int n_in,
                              void* d_out, int out_size, void* d_ws, size_t ws_size,
                              hipStream_t stream)
{
    const float* x       = (const float*)d_in[0];
    const float* w_theta = (const float*)d_in[1];
    const float* w_phi   = (const float*)d_in[2];
    const float* w_g     = (const float*)d_in[3];
    const float* w_out   = (const float*)d_in[4];
    float* out = (float*)d_out;

    float* ws    = (float*)d_ws;
    float* q_p   = ws;                                    // 2*2304*64
    float* phi_p = q_p + (size_t)BATCH * HWPIX * NHEAD;   // 2*4*PLANE
    float* g_p   = phi_p + (size_t)BATCH * TC * PLANE;    // 2*4*PLANE
    float4* wq4  = (float4*)(g_p + (size_t)BATCH * TC * PLANE);
    float4* wp4  = wq4 + 2048;
    float4* wg4  = wp4 + 2048;
    float*  wo_t = (float*)(wg4 + 2048);                  // 64*128

    wtrans_kernel<<<1, 256, 0, stream>>>(w_theta, w_phi, w_g, w_out,
                                         wq4, wp4, wg4, wo_t);

    dim3 g1(HWPIX / 16, BATCH * TT);            // (144, 10) = 1440 blocks
    proj_kernel<<<g1, 256, 0, stream>>>(x, wq4, wp4, wg4, q_p, phi_p, g_p);

    dim3 g2(WW / 16, HH, BATCH);                // (3, 48, 2) = 288 blocks
    attn_kernel<<<g2, 256, 0, stream>>>(q_p, phi_p, g_p, x, wo_t, out);
}

// Round 7
// 142.472 us; speedup vs baseline: 2.0933x; 1.0283x over previous
//
#include <hip/hip_runtime.h>
#include <hip/hip_bf16.h>
#include <math.h>

// B=2, C=128, T=5 (Tc=4 ctx), H=W=48, heads=64, PATCH=7 (pad 3), K=196.
#define BATCH 2
#define CCH 128
#define TT 5
#define TC 4
#define HH 48
#define WW 48
#define HWPIX 2304
#define NHEAD 64
#define PAD 3
#define XSTRIDE (TT*HWPIX)      // per-channel stride in x
#define ROWP 54                 // 48 + 2*3 padded rows
#define COLP 56                 // 48 + 2*3 padded cols (+2 align slack)
#define PLANE (ROWP*COLP*NHEAD) // elements per (b,t) plane

typedef unsigned short bf16_t;

static __device__ __forceinline__ bf16_t f2bf(float f) {
    unsigned u = __float_as_uint(f);
    u += 0x7FFFu + ((u >> 16) & 1u);          // round-to-nearest-even
    return (bf16_t)(u >> 16);
}
static __device__ __forceinline__ float bf_lo(unsigned u) {  // low ushort
    return __uint_as_float(u << 16);
}
static __device__ __forceinline__ float bf_hi(unsigned u) {  // high ushort
    return __uint_as_float(u & 0xFFFF0000u);
}

// ---------------------------------------------------------------------------
// K0: weight reshapes. wq4/wp4/wg4: [32cq][64h] float4 (lane=head).
// wo_t: [64h][128c] transpose of w_out.
// ---------------------------------------------------------------------------
__global__ __launch_bounds__(256) void wtrans_kernel(
    const float* __restrict__ w_theta,
    const float* __restrict__ w_phi,
    const float* __restrict__ w_g,
    const float* __restrict__ w_out,
    float4* __restrict__ wq4,
    float4* __restrict__ wp4,
    float4* __restrict__ wg4,
    float* __restrict__ wo_t)
{
    const int tid = threadIdx.x;
    const float* srcs[3] = {w_theta, w_phi, w_g};
    float4*      dsts[3] = {wq4, wp4, wg4};
#pragma unroll
    for (int a = 0; a < 3; ++a) {
#pragma unroll
        for (int r = 0; r < 8; ++r) {
            const int idx = r * 256 + tid;   // 0..2047
            const int h   = idx >> 5;
            const int cq  = idx & 31;
            dsts[a][cq * 64 + h] = *(const float4*)(srcs[a] + h * CCH + cq * 4);
        }
    }
#pragma unroll
    for (int r = 0; r < 8; ++r) {
        const int idx = r * 256 + tid;       // 0..2047
        const int c   = idx >> 4;
        const int hq  = idx & 15;
        const float4 v = *(const float4*)(w_out + c * NHEAD + hq * 4);
        wo_t[(hq * 4 + 0) * CCH + c] = v.x;
        wo_t[(hq * 4 + 1) * CCH + c] = v.y;
        wo_t[(hq * 4 + 2) * CCH + c] = v.z;
        wo_t[(hq * 4 + 3) * CCH + c] = v.w;
    }
}

// ---------------------------------------------------------------------------
// K1: projections, lane = head, 4 px per wave, depth-1 x-prefetch pipeline.
// q_p fp32 [b][2304][64]; phi_b/g_b BF16 [b][t][54][56][64] replicate borders.
// ---------------------------------------------------------------------------
__global__ __launch_bounds__(256) void proj_kernel(
    const float* __restrict__ x,
    const float4* __restrict__ wq4,
    const float4* __restrict__ wp4,
    const float4* __restrict__ wg4,
    float* __restrict__ q_p,
    bf16_t* __restrict__ phi_b,
    bf16_t* __restrict__ g_b)
{
    const int bt   = blockIdx.y;        // 0..9
    const int b    = bt / TT;
    const int t    = bt % TT;
    const int lane = threadIdx.x & 63;
    const int wv   = __builtin_amdgcn_readfirstlane(threadIdx.x >> 6);
    const int p0   = blockIdx.x * 16 + wv * 4;
    const float* xw = x + ((size_t)(b * CCH) * TT + t) * HWPIX + p0;

    float4 xa[4];
#pragma unroll
    for (int i = 0; i < 4; ++i) xa[i] = *(const float4*)(xw + (size_t)i * XSTRIDE);

    if (t == 0) {
        float acc[4] = {0.f, 0.f, 0.f, 0.f};
#pragma unroll 2
        for (int cq = 0; cq < 32; ++cq) {
            const float4 wq = wq4[(cq << 6) | lane];
            const float wqa[4] = {wq.x, wq.y, wq.z, wq.w};
            float4 xn[4];
            if (cq < 31) {
                const float* xc2 = xw + (size_t)((cq + 1) * 4) * XSTRIDE;
#pragma unroll
                for (int i = 0; i < 4; ++i) xn[i] = *(const float4*)(xc2 + (size_t)i * XSTRIDE);
            }
#pragma unroll
            for (int i = 0; i < 4; ++i) {
                acc[0] = fmaf(wqa[i], xa[i].x, acc[0]);
                acc[1] = fmaf(wqa[i], xa[i].y, acc[1]);
                acc[2] = fmaf(wqa[i], xa[i].z, acc[2]);
                acc[3] = fmaf(wqa[i], xa[i].w, acc[3]);
            }
            if (cq < 31) {
#pragma unroll
                for (int i = 0; i < 4; ++i) xa[i] = xn[i];
            }
        }
#pragma unroll
        for (int p = 0; p < 4; ++p)
            q_p[((size_t)b * HWPIX + p0 + p) * NHEAD + lane] = acc[p];
    } else {
        float accp[4] = {0.f, 0.f, 0.f, 0.f};
        float accg[4] = {0.f, 0.f, 0.f, 0.f};
#pragma unroll 2
        for (int cq = 0; cq < 32; ++cq) {
            const float4 wp = wp4[(cq << 6) | lane];
            const float4 wg = wg4[(cq << 6) | lane];
            const float wpa[4] = {wp.x, wp.y, wp.z, wp.w};
            const float wga[4] = {wg.x, wg.y, wg.z, wg.w};
            float4 xn[4];
            if (cq < 31) {
                const float* xc2 = xw + (size_t)((cq + 1) * 4) * XSTRIDE;
#pragma unroll
                for (int i = 0; i < 4; ++i) xn[i] = *(const float4*)(xc2 + (size_t)i * XSTRIDE);
            }
#pragma unroll
            for (int i = 0; i < 4; ++i) {
                accp[0] = fmaf(wpa[i], xa[i].x, accp[0]);
                accp[1] = fmaf(wpa[i], xa[i].y, accp[1]);
                accp[2] = fmaf(wpa[i], xa[i].z, accp[2]);
                accp[3] = fmaf(wpa[i], xa[i].w, accp[3]);
                accg[0] = fmaf(wga[i], xa[i].x, accg[0]);
                accg[1] = fmaf(wga[i], xa[i].y, accg[1]);
                accg[2] = fmaf(wga[i], xa[i].z, accg[2]);
                accg[3] = fmaf(wga[i], xa[i].w, accg[3]);
            }
            if (cq < 31) {
#pragma unroll
                for (int i = 0; i < 4; ++i) xa[i] = xn[i];
            }
        }
        const size_t base = (size_t)(b * TC + (t - 1)) * PLANE;
#pragma unroll
        for (int p = 0; p < 4; ++p) {
            const int pix = p0 + p;
            const int X = pix / WW;
            const int Y = pix % WW;
            const int rs = (X == 0) ? 0 : (X + PAD);
            const int rn = (X == 0 || X == HH - 1) ? (PAD + 1) : 1;
            const int cs = (Y == 0) ? 0 : (Y + PAD);
            const int cn = (Y == 0 || Y == WW - 1) ? (PAD + 1) : 1;
            const bf16_t vp = f2bf(accp[p]);
            const bf16_t vg = f2bf(accg[p]);
            for (int r = 0; r < rn; ++r)
                for (int c = 0; c < cn; ++c) {
                    const size_t pos = base + ((size_t)(rs + r) * COLP + (cs + c)) * NHEAD + lane;
                    phi_b[pos] = vp;
                    g_b[pos]   = vg;
                }
        }
    }
}

// ---------------------------------------------------------------------------
// K2: per-t attention partial (flash-style). Grid = 1152 blocks:
// blockIdx.x & 7 = b*4+t (XCD-L2 locality), >>3 -> (X, Ytile).
// Block covers 16 px; tid = px(4b)|sub(4b). Stages the 7x22x64 bf16 window
// into swizzled fp32 LDS; 49-key logits; per-t (m,l); unnormalized y partial
// stored bf16.
// ---------------------------------------------------------------------------
__global__ __launch_bounds__(256) void attn_kernel(
    const float* __restrict__ q_p,
    const bf16_t* __restrict__ phi_b,
    const bf16_t* __restrict__ g_b,
    float* __restrict__ part_ml,
    bf16_t* __restrict__ part_y)
{
    __shared__ float win[154 * NHEAD];      // 38.5 KB, swizzled
    __shared__ float ls[16][52];            // 49 exp-weights per px

    const int tid = threadIdx.x;
    const int px  = tid >> 4;
    const int sub = tid & 15;
    const int bi  = blockIdx.x;
    const int btc = bi & 7;                 // b*4 + t
    const int b   = btc >> 2;
    const int t   = btc & 3;
    const int rest = bi >> 3;               // 0..143
    const int Y0  = (rest % 3) * 16;
    const int X   = rest / 3;               // 0..47
    const int gpix = X * WW + Y0 + px;

    // q in regs
    float4 qr[16];
    {
        const float4* qs = (const float4*)(q_p + ((size_t)b * HWPIX + gpix) * NHEAD);
#pragma unroll
        for (int m = 0; m < 16; ++m) qr[m] = qs[m];
    }

    // ---- stage phi window (bf16 -> fp32, swizzled) ----
    {
        const bf16_t* src = phi_b + (size_t)(b * TC + t) * PLANE;
        for (int idx = tid; idx < 1232; idx += 256) {     // 154 rows x 8 chunks
            const int row = idx >> 3;
            const int mq  = (idx & 7) << 1;               // even slot
            const int i   = row / 22;
            const int c   = row - i * 22;
            const uint4 u = *(const uint4*)(src + ((size_t)((X + i) * COLP) + Y0 + c) * NHEAD + mq * 4);
            const int sA = (mq + row) & 15;
            const int sB = (mq + 1 + row) & 15;
            *(float4*)&win[row * 64 + (sA << 2)] =
                make_float4(bf_lo(u.x), bf_hi(u.x), bf_lo(u.y), bf_hi(u.y));
            *(float4*)&win[row * 64 + (sB << 2)] =
                make_float4(bf_lo(u.z), bf_hi(u.z), bf_lo(u.w), bf_hi(u.w));
        }
    }
    __syncthreads();

    // ---- 49-key logits; per-t softmax partial ----
    float v[4];
#pragma unroll
    for (int r = 0; r < 4; ++r) {
        const int k = sub + 16 * r;
        float d = -INFINITY;
        if (k < 49) {
            const int i = k / 7;
            const int j = k - i * 7;
            const int row = i * 22 + j + px;
            const float* base = &win[row * 64];
            float s = 0.f;
#pragma unroll
            for (int m = 0; m < 16; ++m) {
                const float4 a = *(const float4*)&base[((m + row) & 15) << 2];
                const float4 q = qr[m];
                s += a.x*q.x + a.y*q.y + a.z*q.z + a.w*q.w;
            }
            d = s * 8.0f;    // * sqrt(64)
        }
        v[r] = d;
    }
    float m = fmaxf(fmaxf(v[0], v[1]), fmaxf(v[2], v[3]));
#pragma unroll
    for (int d = 1; d < 16; d <<= 1) m = fmaxf(m, __shfl_xor(m, d));
    float lsum = 0.f;
#pragma unroll
    for (int r = 0; r < 4; ++r) {
        const int k = sub + 16 * r;
        if (k < 49) {
            const float e = __expf(v[r] - m);
            ls[px][k] = e;
            lsum += e;
        }
    }
#pragma unroll
    for (int d = 1; d < 16; d <<= 1) lsum += __shfl_xor(lsum, d);
    if (sub == 0) {
        *(float2*)&part_ml[((size_t)(b * TC + t) * HWPIX + gpix) * 2] = make_float2(m, lsum);
    }
    __syncthreads();

    // ---- stage g window ----
    {
        const bf16_t* src = g_b + (size_t)(b * TC + t) * PLANE;
        for (int idx = tid; idx < 1232; idx += 256) {
            const int row = idx >> 3;
            const int mq  = (idx & 7) << 1;
            const int i   = row / 22;
            const int c   = row - i * 22;
            const uint4 u = *(const uint4*)(src + ((size_t)((X + i) * COLP) + Y0 + c) * NHEAD + mq * 4);
            const int sA = (mq + row) & 15;
            const int sB = (mq + 1 + row) & 15;
            *(float4*)&win[row * 64 + (sA << 2)] =
                make_float4(bf_lo(u.x), bf_hi(u.x), bf_lo(u.y), bf_hi(u.y));
            *(float4*)&win[row * 64 + (sB << 2)] =
                make_float4(bf_lo(u.z), bf_hi(u.z), bf_lo(u.w), bf_hi(u.w));
        }
    }
    __syncthreads();

    // ---- unnormalized y partial: thread owns (px, h-chunk sub) ----
    float4 acc = make_float4(0.f, 0.f, 0.f, 0.f);
#pragma unroll
    for (int i = 0; i < 7; ++i) {
#pragma unroll
        for (int j = 0; j < 7; ++j) {
            const int row = i * 22 + j + px;
            const float a = ls[px][i * 7 + j];
            const float4 gv = *(const float4*)&win[row * 64 + (((sub + row) & 15) << 2)];
            acc.x = fmaf(a, gv.x, acc.x);
            acc.y = fmaf(a, gv.y, acc.y);
            acc.z = fmaf(a, gv.z, acc.z);
            acc.w = fmaf(a, gv.w, acc.w);
        }
    }
    ushort4 u4;
    u4.x = f2bf(acc.x); u4.y = f2bf(acc.y); u4.z = f2bf(acc.z); u4.w = f2bf(acc.w);
    *(ushort4*)(part_y + ((size_t)(b * TC + t) * HWPIX + gpix) * NHEAD + (sub << 2)) = u4;
}

// ---------------------------------------------------------------------------
// K3: combine 4 t-partials (exact log-sum-exp merge) + out-proj + residual.
// Grid (3,48,2), 16 px/block, tid = px|sub.
// ---------------------------------------------------------------------------
__global__ __launch_bounds__(256) void combine_kernel(
    const float* __restrict__ x,
    const float* __restrict__ wo_t,
    const float* __restrict__ part_ml,
    const bf16_t* __restrict__ part_y,
    float* __restrict__ out)
{
    __shared__ float y_s[16][68];

    const int tid = threadIdx.x;
    const int px  = tid >> 4;
    const int sub = tid & 15;
    const int Y0  = blockIdx.x * 16;
    const int X   = blockIdx.y;
    const int b   = blockIdx.z;
    const int gpix = X * WW + Y0 + px;

    // merge scales
    const float* mlb = part_ml + ((size_t)b * TC * HWPIX + gpix) * 2;
    float mt[TC], lt[TC];
#pragma unroll
    for (int t = 0; t < TC; ++t) {
        const float2 ml = *(const float2*)(mlb + (size_t)t * HWPIX * 2);
        mt[t] = ml.x; lt[t] = ml.y;
    }
    const float M = fmaxf(fmaxf(mt[0], mt[1]), fmaxf(mt[2], mt[3]));
    float st[TC], L = 0.f;
#pragma unroll
    for (int t = 0; t < TC; ++t) { st[t] = __expf(mt[t] - M); L += lt[t] * st[t]; }
    const float inv = 1.0f / L;
#pragma unroll
    for (int t = 0; t < TC; ++t) st[t] *= inv;

    // combine y partials (bf16)
    float4 acc = make_float4(0.f, 0.f, 0.f, 0.f);
    const bf16_t* pyb = part_y + ((size_t)b * TC * HWPIX + gpix) * NHEAD + (sub << 2);
#pragma unroll
    for (int t = 0; t < TC; ++t) {
        const ushort4 u = *(const ushort4*)(pyb + (size_t)t * HWPIX * NHEAD);
        const float s = st[t];
        acc.x = fmaf(s, __uint_as_float(((unsigned)u.x) << 16), acc.x);
        acc.y = fmaf(s, __uint_as_float(((unsigned)u.y) << 16), acc.y);
        acc.z = fmaf(s, __uint_as_float(((unsigned)u.z) << 16), acc.z);
        acc.w = fmaf(s, __uint_as_float(((unsigned)u.w) << 16), acc.w);
    }
    *(float4*)&y_s[px][sub * 4] = acc;
    __syncthreads();

    // out projection + residual (wo_t[h][c] coalesced)
    {
        const int c0 = sub * 8;
        float o[8];
#pragma unroll
        for (int jj = 0; jj < 8; ++jj) o[jj] = 0.f;
        for (int h0 = 0; h0 < NHEAD; h0 += 4) {
            float yv[4];
            *(float4*)yv = *(const float4*)&y_s[px][h0];
#pragma unroll
            for (int e = 0; e < 4; ++e) {
                const float4 w0 = *(const float4*)(wo_t + (size_t)(h0 + e) * CCH + c0);
                const float4 w1 = *(const float4*)(wo_t + (size_t)(h0 + e) * CCH + c0 + 4);
                const float yy = yv[e];
                o[0] = fmaf(w0.x, yy, o[0]);
                o[1] = fmaf(w0.y, yy, o[1]);
                o[2] = fmaf(w0.z, yy, o[2]);
                o[3] = fmaf(w0.w, yy, o[3]);
                o[4] = fmaf(w1.x, yy, o[4]);
                o[5] = fmaf(w1.y, yy, o[5]);
                o[6] = fmaf(w1.z, yy, o[6]);
                o[7] = fmaf(w1.w, yy, o[7]);
            }
        }
#pragma unroll
        for (int jj = 0; jj < 8; ++jj) {
            const int c = c0 + jj;
            const float xi = x[((size_t)(b * CCH + c) * TT) * HWPIX + gpix];
            out[(size_t)(b * CCH + c) * HWPIX + gpix] = xi + o[jj];
        }
    }
}

// ---------------------------------------------------------------------------
extern "C" void kernel_launch(void* const* d_in, const int* in_sizes, int n_in,
                              void* d_out, int out_size, void* d_ws, size_t ws_size,
                              hipStream_t stream)
{
    const float* x       = (const float*)d_in[0];
    const float* w_theta = (const float*)d_in[1];
    const float* w_phi   = (const float*)d_in[2];
    const float* w_g     = (const float*)d_in[3];
    const float* w_out   = (const float*)d_in[4];
    float* out = (float*)d_out;

    // workspace layout (~10.0 MB total)
    float*  q_p    = (float*)d_ws;                               // 294912 f
    bf16_t* phi_b  = (bf16_t*)(q_p + (size_t)BATCH * HWPIX * NHEAD);
    bf16_t* g_b    = phi_b + (size_t)BATCH * TC * PLANE;
    float4* wq4    = (float4*)(g_b + (size_t)BATCH * TC * PLANE);
    float4* wp4    = wq4 + 2048;
    float4* wg4    = wp4 + 2048;
    float*  wo_t   = (float*)(wg4 + 2048);                       // 8192 f
    float*  part_ml = wo_t + 8192;                               // 36864 f
    bf16_t* part_y  = (bf16_t*)(part_ml + 36864);                // 1179648 us

    wtrans_kernel<<<1, 256, 0, stream>>>(w_theta, w_phi, w_g, w_out,
                                         wq4, wp4, wg4, wo_t);

    dim3 g1(HWPIX / 16, BATCH * TT);            // (144, 10)
    proj_kernel<<<g1, 256, 0, stream>>>(x, wq4, wp4, wg4, q_p, phi_b, g_b);

    attn_kernel<<<BATCH * TC * HH * (WW / 16), 256, 0, stream>>>(
        q_p, phi_b, g_b, part_ml, part_y);      // 1152 blocks

    dim3 g3(WW / 16, HH, BATCH);                // (3, 48, 2)
    combine_kernel<<<g3, 256, 0, stream>>>(x, wo_t, part_ml, part_y, out);
}